// Round 4
// baseline (2468.925 us; speedup 1.0000x reference)
//
#include <hip/hip_runtime.h>
#include <stdint.h>

#define B_     32
#define IMG    56
#define L_     (IMG*IMG)     // 3136
#define C_     384
#define HEADS_ 12
#define HD     32
#define WS_    7
#define N_     49
#define NWIN   64            // 8x8 windows per image
#define NB     (B_*NWIN)     // 2048
#define M_TOK  (NB*N_)       // 100352
#define QKVF   1152

typedef __attribute__((ext_vector_type(8))) short bf16x8;
typedef __attribute__((ext_vector_type(4))) float f32x4;

__device__ __forceinline__ float bf2f(unsigned short u) {
  union { unsigned int u; float f; } c; c.u = ((unsigned int)u) << 16; return c.f;
}
__device__ __forceinline__ unsigned short f2bf(float f) {
  union { float f; unsigned int u; } c; c.f = f;
  unsigned int r = c.u + 0x7FFFu + ((c.u >> 16) & 1u);
  return (unsigned short)(r >> 16);
}

// async global->LDS, 16B per lane. LDS dest semantics: wave-uniform base + lane*16.
__device__ __forceinline__ void gload_lds16(const void* g, void* l) {
  __builtin_amdgcn_global_load_lds(
      (const __attribute__((address_space(1))) unsigned int*)(uintptr_t)g,
      (__attribute__((address_space(3))) unsigned int*)(uintptr_t)l,
      16, 0, 0);
}

#define MFMA16(a, b, c) __builtin_amdgcn_mfma_f32_16x16x32_bf16((a), (b), (c), 0, 0, 0)

// ---------------- fp32 -> bf16 weight conversion ----------------------------
__global__ __launch_bounds__(256) void k_f2b(const float* __restrict__ src,
                                             ushort* __restrict__ dst, int n) {
  int i = blockIdx.x * 256 + threadIdx.x;
  if (i < n) dst[i] = f2bf(src[i]);
}

// ---------------- LayerNorm: fp32 in, bf16 out (+ optional shift+window) ----
// One wave per token (384 ch = 6 per lane). WINDOW=true applies cyclic shift
// (-3,-3) and writes windowed layout.
template<bool WINDOW>
__global__ __launch_bounds__(256) void k_ln(const float* __restrict__ X,
    const float* __restrict__ G, const float* __restrict__ Bb,
    ushort* __restrict__ out)
{
  int token = blockIdx.x * 4 + (threadIdx.x >> 6);
  int lane  = threadIdx.x & 63;
  const float* xp = X + (size_t)token * C_;
  float v[6];
#pragma unroll
  for (int t = 0; t < 6; t++) v[t] = xp[lane + 64*t];
  float s = 0.f, s2 = 0.f;
#pragma unroll
  for (int t = 0; t < 6; t++) { s += v[t]; s2 += v[t]*v[t]; }
#pragma unroll
  for (int off = 32; off > 0; off >>= 1) {
    s  += __shfl_down(s,  off, 64);
    s2 += __shfl_down(s2, off, 64);
  }
  s = __shfl(s, 0, 64); s2 = __shfl(s2, 0, 64);
  float mu   = s * (1.f / C_);
  float rstd = rsqrtf(s2 * (1.f / C_) - mu * mu + 1e-5f);
  size_t obase;
  if (WINDOW) {
    int b = token / L_, pix = token % L_;
    int hi = pix / IMG, wj = pix % IMG;
    int sh = hi - 3; if (sh < 0) sh += IMG;
    int sw = wj - 3; if (sw < 0) sw += IMG;
    int w = b * NWIN + (sh / WS_) * 8 + (sw / WS_);
    int p = (sh % WS_) * WS_ + (sw % WS_);
    obase = ((size_t)w * N_ + p) * C_;
  } else {
    obase = (size_t)token * C_;
  }
#pragma unroll
  for (int t = 0; t < 6; t++) {
    int c = lane + 64*t;
    out[obase + c] = f2bf((v[t] - mu) * rstd * G[c] + Bb[c]);
  }
}

// ---------------- GEMM: C[M,N] = A[M,K] @ W[N,K]^T + bias -------------------
// A, W bf16; bias fp32. m97 structure: 128x128 tile, BK=32, 4 waves, 4x4 MFMAs.
// EPI: 0 = bias only (bf16 out); 1 = bias + window-reverse scatter + fp32
// residual (fp32 out); 2 = bias + gelu (bf16 out); 3 = bias + fp32 residual
// row-aligned, in-place ok (fp32 out).
template<int EPI, typename OutT>
__global__ __launch_bounds__(256, 2) void k_gemm(
    const ushort* __restrict__ A, const ushort* __restrict__ W,
    const float* __restrict__ bias, OutT* __restrict__ out,
    const float* __restrict__ res, int M, int N, int K)
{
  __shared__ __align__(16) ushort As[128*32];
  __shared__ __align__(16) ushort Bs[128*32];
  int ntn = N >> 7;
  int m0 = (blockIdx.x / ntn) << 7;
  int n0 = (blockIdx.x % ntn) << 7;
  int tid  = threadIdx.x;
  int wave = tid >> 6, lane = tid & 63;
  int l15  = lane & 15, quad = lane >> 4;
  int wm = (wave & 1) << 6, wn = (wave >> 1) << 6;

  int srow0 = wave * 32 + (lane >> 2);
  int srow1 = srow0 + 16;
  int scol  = (lane & 3) * 8;
  const ushort* gA0 = A + (size_t)(m0 + srow0) * K + scol;
  const ushort* gA1 = A + (size_t)(m0 + srow1) * K + scol;
  const ushort* gB0 = W + (size_t)(n0 + srow0) * K + scol;
  const ushort* gB1 = W + (size_t)(n0 + srow1) * K + scol;
  ushort* lA0 = &As[srow0 * 32 + scol];
  ushort* lA1 = &As[srow1 * 32 + scol];
  ushort* lB0 = &Bs[srow0 * 32 + scol];
  ushort* lB1 = &Bs[srow1 * 32 + scol];

  f32x4 acc[4][4];
#pragma unroll
  for (int i = 0; i < 4; i++)
#pragma unroll
    for (int j = 0; j < 4; j++) acc[i][j] = (f32x4){0.f, 0.f, 0.f, 0.f};

  for (int k0 = 0; k0 < K; k0 += 32) {
    gload_lds16(gA0, lA0);
    gload_lds16(gA1, lA1);
    gload_lds16(gB0, lB0);
    gload_lds16(gB1, lB1);
    gA0 += 32; gA1 += 32; gB0 += 32; gB1 += 32;
    asm volatile("s_waitcnt vmcnt(0)" : : : "memory");
    __syncthreads();
    bf16x8 af[4], bfr[4];
#pragma unroll
    for (int i = 0; i < 4; i++) af[i]  = *(const bf16x8*)&As[(wm + i*16 + l15)*32 + quad*8];
#pragma unroll
    for (int j = 0; j < 4; j++) bfr[j] = *(const bf16x8*)&Bs[(wn + j*16 + l15)*32 + quad*8];
#pragma unroll
    for (int i = 0; i < 4; i++)
#pragma unroll
      for (int j = 0; j < 4; j++)
        acc[i][j] = MFMA16(af[i], bfr[j], acc[i][j]);
    __syncthreads();
  }

  float bv[4];
#pragma unroll
  for (int j = 0; j < 4; j++) bv[j] = bias[n0 + wn + j*16 + l15];
#pragma unroll
  for (int i = 0; i < 4; i++) {
#pragma unroll
    for (int r = 0; r < 4; r++) {
      int row = m0 + wm + i*16 + quad*4 + r;   // C/D layout: row=quad*4+reg, col=lane&15
      size_t dstbase;
      if (EPI == 1) {
        int w = row / N_, p = row % N_;
        int b = w >> 6, wi = w & 63;
        int hi = (wi >> 3) * WS_ + p / WS_ + 3; if (hi >= IMG) hi -= IMG;
        int wj = (wi & 7)  * WS_ + p % WS_ + 3; if (wj >= IMG) wj -= IMG;
        dstbase = ((size_t)b * L_ + hi * IMG + wj) * C_;
      } else {
        dstbase = (size_t)row * N;
      }
#pragma unroll
      for (int j = 0; j < 4; j++) {
        int col = n0 + wn + j*16 + l15;
        float v = acc[i][j][r] + bv[j];
        if (EPI == 2) {
          float x3 = v * v * v;
          v = 0.5f * v * (1.f + tanhf(0.7978845608028654f * (v + 0.044715f * x3)));
        }
        size_t dst = dstbase + col;
        if (EPI == 1) v += res[dst];
        if (EPI == 3) v += res[(size_t)row * N + col];
        if constexpr (sizeof(OutT) == 4) out[dst] = v;
        else                             out[dst] = f2bf(v);
      }
    }
  }
}

// ---------------- scalar windowed attention (correctness-first) -------------
// 4 waves/block, one wave per (window, head), lane = query index (49 active).
// qkv bf16; relb/mask fp32; out bf16. fp32 math, all reads in-bounds.
__global__ __launch_bounds__(256) void k_attn_scalar(
    const ushort* __restrict__ qkv, const float* __restrict__ relb,
    const float* __restrict__ mask, ushort* __restrict__ out)
{
  int task = blockIdx.x * 4 + (threadIdx.x >> 6);
  int lane = threadIdx.x & 63;
  int w = task / HEADS_, h = task % HEADS_;
  bool act = lane < N_;
  int qi = act ? lane : 0;

  const ushort* base = qkv + (size_t)w * N_ * QKVF + h * HD;
  const ushort* qp = base + (size_t)qi * QKVF;
  float q[HD];
#pragma unroll
  for (int d = 0; d < HD; d++) q[d] = bf2f(qp[d]) * 0.17677669529663687f;

  int ni = qi / WS_, nj = qi % WS_;
  const float* mrow = mask + ((size_t)(w & 63) * N_ + qi) * N_;
  float s[N_];
  float mx = -1e30f;
#pragma unroll
  for (int m = 0; m < N_; m++) {
    const ushort* kp = base + (size_t)m * QKVF + C_;
    float a = 0.f;
#pragma unroll
    for (int d = 0; d < HD; d++) a += q[d] * bf2f(kp[d]);
    int idx = (ni - m / WS_ + 6) * 13 + (nj - m % WS_ + 6);
    a += relb[idx * HEADS_ + h] + mrow[m];
    s[m] = a;
    mx = fmaxf(mx, a);
  }
  float sum = 0.f;
#pragma unroll
  for (int m = 0; m < N_; m++) { float e = __expf(s[m] - mx); s[m] = e; sum += e; }
  float inv = 1.f / sum;

  float o[HD];
#pragma unroll
  for (int d = 0; d < HD; d++) o[d] = 0.f;
#pragma unroll
  for (int m = 0; m < N_; m++) {
    float p = s[m] * inv;
    const ushort* vp = base + (size_t)m * QKVF + 2 * C_;
#pragma unroll
    for (int d = 0; d < HD; d++) o[d] += p * bf2f(vp[d]);
  }
  if (act) {
    ushort* op = out + ((size_t)w * N_ + lane) * C_ + h * HD;
#pragma unroll
    for (int d = 0; d < HD; d++) op[d] = f2bf(o[d]);
  }
}

// ---------------------------------------------------------------------------
extern "C" void kernel_launch(void* const* d_in, const int* in_sizes, int n_in,
                              void* d_out, int out_size, void* d_ws, size_t ws_size,
                              hipStream_t stream) {
  (void)in_sizes; (void)n_in; (void)out_size; (void)ws_size;
  const float* x      = (const float*)d_in[0];
  const float* mask   = (const float*)d_in[1];
  const float* w_ln1  = (const float*)d_in[2];
  const float* b_ln1  = (const float*)d_in[3];
  const float* w_qkv  = (const float*)d_in[4];
  const float* b_qkv  = (const float*)d_in[5];
  const float* relb   = (const float*)d_in[6];
  const float* w_proj = (const float*)d_in[7];
  const float* b_proj = (const float*)d_in[8];
  const float* w_ln2  = (const float*)d_in[9];
  const float* b_ln2  = (const float*)d_in[10];
  const float* w_fc1  = (const float*)d_in[11];
  const float* b_fc1  = (const float*)d_in[12];
  const float* w_fc2  = (const float*)d_in[13];
  const float* b_fc2  = (const float*)d_in[14];

  // ws (bf16 internals):
  //   r0 [0, 308,281,344)                  qkv (231MB) -> mlp hidden (308MB)
  //   r1 [308,281,344, +77,070,336)        hw -> attn_out -> h2
  //   wb [385,351,680, +3,538,944)         bf16 weights: qkv|proj|fc1|fc2
  // total = 388,890,624 B. x1 lives in d_out (fp32).
  char* ws = (char*)d_ws;
  ushort* r0 = (ushort*)ws;
  ushort* r1 = (ushort*)(ws + 308281344);
  ushort* wbq = (ushort*)(ws + 385351680);
  ushort* wbp = wbq + QKVF * C_;          // 442368
  ushort* wb1 = wbp + C_ * C_;            // +147456
  ushort* wb2 = wb1 + 1536 * C_;          // +589824
  float*  x1   = (float*)d_out;
  float*  outp = (float*)d_out;

  k_f2b<<<(QKVF*C_ + 255)/256, 256, 0, stream>>>(w_qkv,  wbq, QKVF*C_);
  k_f2b<<<(C_*C_   + 255)/256, 256, 0, stream>>>(w_proj, wbp, C_*C_);
  k_f2b<<<(1536*C_ + 255)/256, 256, 0, stream>>>(w_fc1,  wb1, 1536*C_);
  k_f2b<<<(C_*1536 + 255)/256, 256, 0, stream>>>(w_fc2,  wb2, C_*1536);

  k_ln<true ><<<M_TOK/4, 256, 0, stream>>>(x, w_ln1, b_ln1, r1);                 // r1 = hw
  k_gemm<0, ushort><<<(M_TOK/128)*(QKVF/128), 256, 0, stream>>>(
      r1, wbq, b_qkv, r0, nullptr, M_TOK, QKVF, 384);                            // r0 = qkv
  k_attn_scalar<<<NB*HEADS_/4, 256, 0, stream>>>(r0, relb, mask, r1);            // r1 = attn_out
  k_gemm<1, float><<<(M_TOK/128)*(C_/128), 256, 0, stream>>>(
      r1, wbp, b_proj, x1, x, M_TOK, C_, 384);                                   // x1 = x + o (fp32)
  k_ln<false><<<M_TOK/4, 256, 0, stream>>>(x1, w_ln2, b_ln2, r1);                // r1 = h2
  k_gemm<2, ushort><<<(M_TOK/128)*(1536/128), 256, 0, stream>>>(
      r1, wb1, b_fc1, r0, nullptr, M_TOK, 1536, 384);                            // r0 = hidden
  k_gemm<3, float><<<(M_TOK/128)*(C_/128), 256, 0, stream>>>(
      r0, wb2, b_fc2, outp, x1, M_TOK, C_, 1536);                                // out (fp32)
}